// Round 2
// 1271.213 us; speedup vs baseline: 1.0749x; 1.0749x over previous
//
#include <hip/hip_runtime.h>
#include <stdint.h>

#define BT 2048
#define H  2048
#define V  32000

typedef __attribute__((ext_vector_type(8))) short short8;
typedef __attribute__((ext_vector_type(4))) float f32x4;

__device__ inline unsigned short f2bf(float x) {
  unsigned int u = __float_as_uint(x);
  u += 0x7FFFu + ((u >> 16) & 1u);   // round-to-nearest-even
  return (unsigned short)(u >> 16);
}

// ---------------- kernel 0: zero the accumulator ----------------
__global__ void zero_accum(float* accum) {
  accum[0] = 0.0f;
  ((unsigned int*)accum)[1] = 0u;
}

// ---------------- kernel 1: fp32 -> bf16 convert (8 elems/thread) ----------------
__global__ __launch_bounds__(256) void cvt_kernel(const float* __restrict__ src,
                                                  unsigned short* __restrict__ dst,
                                                  int n8) {
  int i = blockIdx.x * blockDim.x + threadIdx.x;
  if (i >= n8) return;
  const float4* s = (const float4*)src;
  float4 a = s[2 * i];
  float4 b = s[2 * i + 1];
  union { unsigned short us[8]; uint4 v; } o;
  o.us[0] = f2bf(a.x); o.us[1] = f2bf(a.y); o.us[2] = f2bf(a.z); o.us[3] = f2bf(a.w);
  o.us[4] = f2bf(b.x); o.us[5] = f2bf(b.y); o.us[6] = f2bf(b.z); o.us[7] = f2bf(b.w);
  ((uint4*)dst)[i] = o.v;
}

// ---------------- kernel 2: bf16 NT GEMM (C = A @ B^T) ----------------
// 256x256 tile, BK=32, 8 waves, 4-deep LDS ring (128 KiB), counted-vmcnt pipeline.
// A: [BT,H] row-major, B: [V,H] row-major (K contiguous in both), C: [BT,V] bf16.
// gridDim.x = 8 = #XCDs -> blockIdx.x == XCD id (round-robin on linear id), so each
// XCD keeps one 1 MB A-panel resident in its L2 while sweeping n-tiles (T1 for free).
#define GBM 256
#define GBN 256
#define GBK 32
#define NKT (H / GBK)   // 64 K-tiles

// Swizzle (T2): within each tile buffer (256 rows x 4 16B-chunks), physical chunk
//   p = (row>>1)*8 + ((cc*2 + (row&1)) ^ (row&6))
// Bijective per row-pair; a 16-lane fragment read (rows r0..r0+15, fixed cc) maps to
// physical chunks covering all 32 banks exactly 2-way (free per m136).  gload_lds
// writes LDS linearly, so the *global source* gets the inverse permutation (rule #21).

#define GLL(gp, lp) __builtin_amdgcn_global_load_lds( \
    (const __attribute__((address_space(1))) unsigned int*)(gp), \
    (__attribute__((address_space(3))) unsigned int*)(lp), 16, 0, 0)

__global__ __launch_bounds__(512, 2) void gemm_bt(const unsigned short* __restrict__ A0,
                                                  const unsigned short* __restrict__ B0,
                                                  const unsigned short* __restrict__ A1,
                                                  const unsigned short* __restrict__ B1,
                                                  unsigned short* __restrict__ C0,
                                                  unsigned short* __restrict__ C1) {
  const int z = blockIdx.z;
  const unsigned short* Amat = z ? A1 : A0;
  const unsigned short* Bmat = z ? B1 : B0;
  unsigned short* C = z ? C1 : C0;

  const int m0 = blockIdx.x * GBM;   // 8 m-tiles  (== XCD id)
  const int n0 = blockIdx.y * GBN;   // 125 n-tiles

  __shared__ alignas(16) unsigned short lA[4][8192];   // 4 bufs x 256x32 bf16 = 64 KiB
  __shared__ alignas(16) unsigned short lB[4][8192];   // 64 KiB

  const int tid  = threadIdx.x;
  const int lane = tid & 63;
  const int w    = tid >> 6;     // wave 0..7
  const int wm   = w >> 2;       // 0..1  (wave owns rows wm*128..+127)
  const int wn   = w & 3;        // 0..3  (wave owns cols wn*64..+63)
  const int l4   = lane & 15;
  const int q    = lane >> 4;    // k-chunk 0..3

  // ---- staging source addresses (inverse swizzle) ----
  // thread stages physical chunks p = tid + j*512 of each buffer
  const unsigned short* ga[2];
  const unsigned short* gb[2];
  #pragma unroll
  for (int j = 0; j < 2; j++) {
    int p   = tid + j * 512;
    int pr  = p >> 3;                          // row-pair
    int s0  = (p & 7) ^ ((pr & 3) << 1);       // undo XOR
    int row = (pr << 1) | (s0 & 1);
    int cc  = s0 >> 1;                         // 16B k-chunk 0..3
    ga[j] = Amat + (size_t)(m0 + row) * H + cc * 8;
    gb[j] = Bmat + (size_t)(n0 + row) * H + cc * 8;
  }

  // ---- fragment read bases (swizzled): frag mf/nf at +mf*512 elements ----
  const int s0f   = ((q << 1) | (l4 & 1)) ^ (l4 & 6);
  const int Abase = (wm * 64 + (l4 >> 1)) * 64 + s0f * 8;
  const int Bbase = (wn * 32 + (l4 >> 1)) * 64 + s0f * 8;

  f32x4 acc[8][4];
  #pragma unroll
  for (int i = 0; i < 8; i++)
    #pragma unroll
    for (int j = 0; j < 4; j++)
      acc[i][j] = (f32x4){0.f, 0.f, 0.f, 0.f};

  // ---- prologue: stage tiles 0,1,2 into buffers 0,1,2 (12 loads/thread) ----
  #pragma unroll
  for (int t = 0; t < 3; t++) {
    GLL(ga[0] + t * GBK, &lA[t][w * 512]);
    GLL(ga[1] + t * GBK, &lA[t][w * 512 + 4096]);
    GLL(gb[0] + t * GBK, &lB[t][w * 512]);
    GLL(gb[1] + t * GBK, &lB[t][w * 512 + 4096]);
  }
  asm volatile("s_waitcnt vmcnt(8)" ::: "memory");   // tile 0 landed; 1,2 in flight
  __builtin_amdgcn_s_barrier();

  for (int t = 0; t < NKT; ++t) {
    const int cur = t & 3;
    const bool st = (t + 3) < NKT;
    const int  sb = (t + 3) & 3;

    // ---------- phase A: frags + A-stage, MFMA quadrant mf 0..3 ----------
    short8 af[4], bf[4];
    #pragma unroll
    for (int mf = 0; mf < 4; mf++) af[mf] = *(const short8*)&lA[cur][Abase + mf * 512];
    #pragma unroll
    for (int nf = 0; nf < 4; nf++) bf[nf] = *(const short8*)&lB[cur][Bbase + nf * 512];
    if (st) {
      GLL(ga[0] + (t + 3) * GBK, &lA[sb][w * 512]);
      GLL(ga[1] + (t + 3) * GBK, &lA[sb][w * 512 + 4096]);
    }
    __builtin_amdgcn_s_barrier();
    asm volatile("s_waitcnt lgkmcnt(0)" ::: "memory");
    __builtin_amdgcn_s_setprio(1);
    #pragma unroll
    for (int mf = 0; mf < 4; mf++)
      #pragma unroll
      for (int nf = 0; nf < 4; nf++)
        acc[mf][nf] = __builtin_amdgcn_mfma_f32_16x16x32_bf16(af[mf], bf[nf], acc[mf][nf], 0, 0, 0);
    __builtin_amdgcn_s_setprio(0);
    __builtin_amdgcn_s_barrier();

    // ---------- phase B: frags + B-stage, MFMA quadrant mf 4..7 ----------
    short8 ag[4];
    #pragma unroll
    for (int mf = 0; mf < 4; mf++) ag[mf] = *(const short8*)&lA[cur][Abase + (mf + 4) * 512];
    if (st) {
      GLL(gb[0] + (t + 3) * GBK, &lB[sb][w * 512]);
      GLL(gb[1] + (t + 3) * GBK, &lB[sb][w * 512 + 4096]);
    }
    __builtin_amdgcn_s_barrier();
    asm volatile("s_waitcnt lgkmcnt(0)" ::: "memory");
    __builtin_amdgcn_s_setprio(1);
    #pragma unroll
    for (int mf = 0; mf < 4; mf++)
      #pragma unroll
      for (int nf = 0; nf < 4; nf++)
        acc[mf + 4][nf] = __builtin_amdgcn_mfma_f32_16x16x32_bf16(ag[mf], bf[nf], acc[mf + 4][nf], 0, 0, 0);
    __builtin_amdgcn_s_setprio(0);

    // ---- end of tile: guarantee tile t+1 resident; keep 8 loads in flight ----
    if (t < NKT - 3)       asm volatile("s_waitcnt vmcnt(8)" ::: "memory");
    else if (t == NKT - 3) asm volatile("s_waitcnt vmcnt(4)" ::: "memory");
    else                   asm volatile("s_waitcnt vmcnt(0)" ::: "memory");
    __builtin_amdgcn_s_barrier();
  }

  // ---- epilogue: C/D layout col=lane&15, row=quad*4+reg (m89-verified) ----
  #pragma unroll
  for (int mf = 0; mf < 8; mf++)
    #pragma unroll
    for (int nf = 0; nf < 4; nf++)
      #pragma unroll
      for (int r = 0; r < 4; r++) {
        int gr = m0 + wm * 128 + mf * 16 + q * 4 + r;
        int gc = n0 + wn * 64 + nf * 16 + l4;
        C[(size_t)gr * V + gc] = f2bf(acc[mf][nf][r]);
      }
}

// ---------------- kernel 3: per-row JSD (2 passes: online max+sumexp, then loss) ----------------
__device__ inline void unpack8(uint4 v, float* f) {
  f[0] = __uint_as_float(v.x << 16);
  f[1] = __uint_as_float(v.x & 0xFFFF0000u);
  f[2] = __uint_as_float(v.y << 16);
  f[3] = __uint_as_float(v.y & 0xFFFF0000u);
  f[4] = __uint_as_float(v.z << 16);
  f[5] = __uint_as_float(v.z & 0xFFFF0000u);
  f[6] = __uint_as_float(v.w << 16);
  f[7] = __uint_as_float(v.w & 0xFFFF0000u);
}

__device__ inline float blk_max(float v, float* red, int tid) {
  #pragma unroll
  for (int o = 32; o > 0; o >>= 1) v = fmaxf(v, __shfl_xor(v, o, 64));
  __syncthreads();
  if ((tid & 63) == 0) red[tid >> 6] = v;
  __syncthreads();
  return fmaxf(fmaxf(red[0], red[1]), fmaxf(red[2], red[3]));
}

__device__ inline float blk_sum(float v, float* red, int tid) {
  #pragma unroll
  for (int o = 32; o > 0; o >>= 1) v += __shfl_xor(v, o, 64);
  __syncthreads();
  if ((tid & 63) == 0) red[tid >> 6] = v;
  __syncthreads();
  return (red[0] + red[1]) + (red[2] + red[3]);
}

__global__ __launch_bounds__(256) void jsd_kernel(const unsigned short* __restrict__ Slog,
                                                  const unsigned short* __restrict__ Tlog,
                                                  const long long* __restrict__ labels,
                                                  float* __restrict__ accum) {
  const int r   = blockIdx.x;
  const int tid = threadIdx.x;
  __shared__ float red[4];

  const uint4* s4 = (const uint4*)(Slog + (size_t)r * V);
  const uint4* t4 = (const uint4*)(Tlog + (size_t)r * V);
  const int NC = V / 8;   // 4000 chunks of 8 bf16

  // pass 1: fused online max + sum-exp (exact LSE, one read instead of two)
  float sm = -1e30f, ss = 0.f, tm = -1e30f, ts = 0.f;
  for (int c = tid; c < NC; c += 256) {
    uint4 sv = s4[c], tv = t4[c];
    float fs[8], ft[8];
    unpack8(sv, fs); unpack8(tv, ft);
    float lms = fs[0], lmt = ft[0];
    #pragma unroll
    for (int j = 1; j < 8; j++) { lms = fmaxf(lms, fs[j]); lmt = fmaxf(lmt, ft[j]); }
    if (lms > sm) { ss *= __expf(sm - lms); sm = lms; }
    if (lmt > tm) { ts *= __expf(tm - lmt); tm = lmt; }
    #pragma unroll
    for (int j = 0; j < 8; j++) {
      ss += __expf(fs[j] - sm);
      ts += __expf(ft[j] - tm);
    }
  }
  float SM = blk_max(sm, red, tid);
  ss *= __expf(sm - SM);
  float SS = blk_sum(ss, red, tid);
  float TM = blk_max(tm, red, tid);
  ts *= __expf(tm - TM);
  float TS = blk_sum(ts, red, tid);
  float slse = SM + __logf(SS);
  float tlse = TM + __logf(TS);

  // pass 2: JSD terms (beta = 0.5)
  float loss = 0.f;
  for (int c = tid; c < NC; c += 256) {
    uint4 sv = s4[c], tv = t4[c];
    float fs[8], ft[8];
    unpack8(sv, fs); unpack8(tv, ft);
    #pragma unroll
    for (int j = 0; j < 8; j++) {
      float sl = fs[j] - slse;        // log Q
      float tl = ft[j] - tlse;        // log P
      float qv = __expf(sl);
      float pv = __expf(tl);
      float m  = 0.5f * (pv + qv);
      float lm = __logf(m);
      loss += 0.5f * (pv * (tl - lm) + qv * (sl - lm));
    }
  }
  loss = blk_sum(loss, red, tid);

  if (tid == 0) {
    long long lab = labels[r];
    if (lab != -100LL) {
      atomicAdd(&accum[0], loss);
      atomicAdd((unsigned int*)&accum[1], 1u);
    }
  }
}

// ---------------- kernel 4: finalize ----------------
__global__ void finalize(const float* __restrict__ accum, float* __restrict__ out) {
  float cnt = (float)((const unsigned int*)accum)[1];
  out[0] = accum[0] / fmaxf(cnt, 1.0f);
}

extern "C" void kernel_launch(void* const* d_in, const int* in_sizes, int n_in,
                              void* d_out, int out_size, void* d_ws, size_t ws_size,
                              hipStream_t stream) {
  const float* s_in = (const float*)d_in[0];
  const float* s_w  = (const float*)d_in[1];
  const float* t_in = (const float*)d_in[2];
  const float* t_w  = (const float*)d_in[3];
  const long long* labels = (const long long*)d_in[4];
  float* out = (float*)d_out;

  // workspace layout
  char* ws = (char*)d_ws;
  size_t off = 0;
  auto take = [&](size_t bytes) -> char* {
    char* p = ws + off;
    off += (bytes + 255) & ~(size_t)255;
    return p;
  };
  unsigned short* sw_bf = (unsigned short*)take((size_t)V * H * 2);
  unsigned short* tw_bf = (unsigned short*)take((size_t)V * H * 2);
  unsigned short* si_bf = (unsigned short*)take((size_t)BT * H * 2);
  unsigned short* ti_bf = (unsigned short*)take((size_t)BT * H * 2);
  unsigned short* slog  = (unsigned short*)take((size_t)BT * V * 2);
  unsigned short* tlog  = (unsigned short*)take((size_t)BT * V * 2);
  float* accum = (float*)take(256);
  if (off > ws_size) return;  // workspace too small: bail (will show as wrong answer)

  zero_accum<<<dim3(1), dim3(1), 0, stream>>>(accum);

  const int nW8 = (V * H) / 8;   // 8,192,000
  const int nI8 = (BT * H) / 8;  // 524,288
  cvt_kernel<<<dim3((nW8 + 255) / 256), dim3(256), 0, stream>>>(s_w, sw_bf, nW8);
  cvt_kernel<<<dim3((nW8 + 255) / 256), dim3(256), 0, stream>>>(t_w, tw_bf, nW8);
  cvt_kernel<<<dim3((nI8 + 255) / 256), dim3(256), 0, stream>>>(s_in, si_bf, nI8);
  cvt_kernel<<<dim3((nI8 + 255) / 256), dim3(256), 0, stream>>>(t_in, ti_bf, nI8);

  gemm_bt<<<dim3(BT / GBM, V / GBN, 2), dim3(512), 0, stream>>>(si_bf, sw_bf, ti_bf, tw_bf, slog, tlog);

  jsd_kernel<<<dim3(BT), dim3(256), 0, stream>>>(slog, tlog, labels, accum);

  finalize<<<dim3(1), dim3(1), 0, stream>>>(accum, out);
}